// Round 9
// baseline (371.505 us; speedup 1.0000x reference)
//
#include <hip/hip_runtime.h>
#include <hip/hip_bf16.h>
#include <cstddef>
#include <cstdint>

#define B_N 2
#define L_N 2048
#define DM_N 1024
#define DS_N 16
#define DI_N 2048
#define NTOK (B_N * L_N)   // 4096
#define NPROJ 33           // 2*DS+1
#define NPJ 36             // padded proj row: d0@0, B@4..19, C@20..35
#define NC 64              // scan chunks
#define CL (L_N / NC)      // 32 steps per chunk
#define XKC 8              // xproj K-split
#define XKCL (DI_N / XKC)  // 256

typedef __attribute__((ext_vector_type(8))) short short8v;
typedef __attribute__((ext_vector_type(4))) float f32x4;
typedef __attribute__((address_space(1))) void av1;
typedef __attribute__((address_space(3))) void av3;

__device__ __forceinline__ void gload16(const void* g, void* l) {
  __builtin_amdgcn_global_load_lds((av1*)g, (av3*)l, 16, 0, 0);
}

__device__ __forceinline__ unsigned short f2bf_rn(float f) {
  uint32_t u = __float_as_uint(f);
  uint32_t r = (u + 0x7fffu + ((u >> 16) & 1u)) >> 16;
  return (unsigned short)r;
}
__device__ __forceinline__ float bf2f(unsigned short h) {
  return __uint_as_float((uint32_t)h << 16);
}

// ---------------------------------------------------------------------------
// Split fp32 -> packed [row][kgroup8][16B hi | 16B lo]. 8 elements/thread.
// ---------------------------------------------------------------------------
__global__ __launch_bounds__(256) void split_pack_kernel(
    const float* __restrict__ src, uint32_t* __restrict__ dst, int n8) {
  int idx = blockIdx.x * 256 + threadIdx.x;
  if (idx >= n8) return;
  const float4* s = (const float4*)src + (size_t)idx * 2;
  float4 v0 = s[0], v1 = s[1];
  float f[8] = {v0.x, v0.y, v0.z, v0.w, v1.x, v1.y, v1.z, v1.w};
  uint32_t hi[4], lo[4];
#pragma unroll
  for (int j = 0; j < 4; ++j) {
    unsigned short h0 = f2bf_rn(f[2 * j]);
    unsigned short h1 = f2bf_rn(f[2 * j + 1]);
    unsigned short l0 = f2bf_rn(f[2 * j] - bf2f(h0));
    unsigned short l1 = f2bf_rn(f[2 * j + 1] - bf2f(h1));
    hi[j] = (uint32_t)h0 | ((uint32_t)h1 << 16);
    lo[j] = (uint32_t)l0 | ((uint32_t)l1 << 16);
  }
  uint4* d = (uint4*)dst + (size_t)idx * 2;
  d[0] = make_uint4(hi[0], hi[1], hi[2], hi[3]);
  d[1] = make_uint4(lo[0], lo[1], lo[2], lo[3]);
}

// ---------------------------------------------------------------------------
// Packed split-bf16 NT GEMM (single dispatch per GEMM; kshift kept but 0).
// LDS swizzle: physical slot p at row r holds logical slot p^(r&7)^((r>>3)&1),
// baked into the per-lane global source address (linear gload_lds dest).
// ---------------------------------------------------------------------------
__global__ __launch_bounds__(256) void gemm_pk_nt(
    const char* __restrict__ Apk, const char* __restrict__ Bpk,
    float* __restrict__ C, int N, int K4, int gx,
    int kshift, int K4half, size_t cstride) {
  __shared__ __align__(16) char lds[32768];
  const int tid = threadIdx.x;
  const int lane = tid & 63;
  const int wave = tid >> 6;

  const int nwg = gridDim.x;
  const int cpx = nwg >> 3;
  const int bid = blockIdx.x;
  const int wg = (bid & 7) * cpx + (bid >> 3);
  const int kc = wg & ((1 << kshift) - 1);
  const int tile = wg >> kshift;
  const int bx = tile % gx;
  const int by = tile / gx;
  const int m0 = by * 128, n0 = bx * 128;

  const int wr = wave >> 1, wc = wave & 1;

  const char* gbase = (wave & 2) ? Bpk : Apk;
  const int rowbase = ((wave & 2) ? n0 : m0) + (wave & 1) * 64;
  const int rloc = lane >> 3;
  const int sslot = (lane & 7) ^ rloc;
  const char* gsrc = gbase + (size_t)(rowbase + rloc) * K4 + sslot * 16;
  const size_t rstride = (size_t)8 * K4;
  char* ldst = lds + wave * 8192 + lane * 16;

  f32x4 acc[4][4] = {};
  const int fr = lane & 15;
  const int fg = lane >> 4;
  const int sA = ((fg * 2) ^ (fr & 7) ^ ((fr >> 3) & 1)) * 16;
  const int abase = (wr * 64 + fr) * 128 + sA;
  const int bbase = 16384 + (wc * 64 + fr) * 128 + sA;

  const int kt4b = kc * K4half;
  const int kt4e = kt4b + K4half;
  for (int kt4 = kt4b; kt4 < kt4e; kt4 += 128) {
#pragma unroll
    for (int c = 0; c < 8; ++c) {
      const char* p = (const char*)((uintptr_t)(gsrc + c * rstride) ^ ((c & 1) << 4));
      gload16(p + kt4, ldst + c * 1024);
    }
    __syncthreads();

    short8v afh[4], afl[4], bfh[4], bfl[4];
#pragma unroll
    for (int m = 0; m < 4; ++m) {
      int a = abase + m * 2048;
      afh[m] = *(const short8v*)(lds + a);
      afl[m] = *(const short8v*)(lds + (a ^ 16));
    }
#pragma unroll
    for (int n = 0; n < 4; ++n) {
      int b = bbase + n * 2048;
      bfh[n] = *(const short8v*)(lds + b);
      bfl[n] = *(const short8v*)(lds + (b ^ 16));
    }
#pragma unroll
    for (int m = 0; m < 4; ++m) {
#pragma unroll
      for (int n = 0; n < 4; ++n) {
        asm("v_mfma_f32_16x16x32_bf16 %0, %1, %2, %0"
            : "+v"(acc[m][n]) : "v"(afh[m]), "v"(bfh[n]));
        asm("v_mfma_f32_16x16x32_bf16 %0, %1, %2, %0"
            : "+v"(acc[m][n]) : "v"(afh[m]), "v"(bfl[n]));
        asm("v_mfma_f32_16x16x32_bf16 %0, %1, %2, %0"
            : "+v"(acc[m][n]) : "v"(afl[m]), "v"(bfh[n]));
      }
    }
    __syncthreads();
  }

  float* Cout = C + (size_t)kc * cstride;
#pragma unroll
  for (int m = 0; m < 4; ++m) {
#pragma unroll
    for (int n = 0; n < 4; ++n) {
#pragma unroll
      for (int q = 0; q < 4; ++q) {
        int row = m0 + wr * 64 + m * 16 + fg * 4 + q;
        int col = n0 + wc * 64 + n * 16 + fr;
        Cout[(size_t)row * N + col] = acc[m][n][q];
      }
    }
  }
}

// ---------------------------------------------------------------------------
// Depthwise causal conv (DC=4) + bias, times silu(z). float4 over channels.
// ---------------------------------------------------------------------------
__global__ __launch_bounds__(256) void conv_silu_kernel(
    const float* __restrict__ xz, const float* __restrict__ cw,
    const float* __restrict__ cb, float* __restrict__ u2) {
  int idx = blockIdx.x * 256 + threadIdx.x;  // < NTOK*DI/4 = 2097152
  int i4 = idx & (DI_N / 4 - 1);
  int n = idx >> 9;
  int i = i4 << 2;
  int l = n & (L_N - 1);
  const float* base = xz + (size_t)n * (2 * DI_N) + i;
  float4 zero = {0.f, 0.f, 0.f, 0.f};
  float4 u0 = *(const float4*)base;
  float4 u1 = (l >= 1) ? *(const float4*)(base - 2 * DI_N) : zero;
  float4 um2 = (l >= 2) ? *(const float4*)(base - 4 * DI_N) : zero;
  float4 um3 = (l >= 3) ? *(const float4*)(base - 6 * DI_N) : zero;
  float4 z = *(const float4*)(base + DI_N);
  float4 bia = *(const float4*)&cb[i];
  float4 w0 = *(const float4*)&cw[i * 4];
  float4 w1 = *(const float4*)&cw[i * 4 + 4];
  float4 w2 = *(const float4*)&cw[i * 4 + 8];
  float4 w3 = *(const float4*)&cw[i * 4 + 12];
  float4 r;
  r.x = fmaf(w0.w, u0.x, fmaf(w0.z, u1.x, fmaf(w0.y, um2.x, fmaf(w0.x, um3.x, bia.x))));
  r.y = fmaf(w1.w, u0.y, fmaf(w1.z, u1.y, fmaf(w1.y, um2.y, fmaf(w1.x, um3.y, bia.y))));
  r.z = fmaf(w2.w, u0.z, fmaf(w2.z, u1.z, fmaf(w2.y, um2.z, fmaf(w2.x, um3.z, bia.z))));
  r.w = fmaf(w3.w, u0.w, fmaf(w3.z, u1.w, fmaf(w3.y, um2.w, fmaf(w3.x, um3.w, bia.w))));
  r.x *= z.x / (1.f + __expf(-z.x));
  r.y *= z.y / (1.f + __expf(-z.y));
  r.z *= z.z / (1.f + __expf(-z.z));
  r.w *= z.w / (1.f + __expf(-z.w));
  *(float4*)&u2[(size_t)n * DI_N + i] = r;
}

// ---------------------------------------------------------------------------
// xproj stage 1: partials into padded 36-wide rows (d0@0, B@4..19, C@20..35).
// Slots 1..3 are zero-filled so no ws byte is ever read uninitialized.
// ---------------------------------------------------------------------------
__global__ __launch_bounds__(256) void xproj_part_kernel(
    const float* __restrict__ u2, const float* __restrict__ xw,
    float* __restrict__ part) {
  __shared__ float uS[16][257];
  __shared__ float wS[33][257];
  const int tid = threadIdx.x;
  const int kc = blockIdx.x & (XKC - 1);
  const int rb = blockIdx.x >> 3;
  const int row0 = rb * 16;
  const int k0 = kc * XKCL;

#pragma unroll
  for (int it = 0; it < 4; ++it) {
    int slot = tid + it * 256;
    int r = slot >> 6;
    int kq = (slot & 63) << 2;
    float4 v = *(const float4*)&u2[(size_t)(row0 + r) * DI_N + k0 + kq];
    uS[r][kq] = v.x; uS[r][kq + 1] = v.y;
    uS[r][kq + 2] = v.z; uS[r][kq + 3] = v.w;
  }
#pragma unroll
  for (int it = 0; it < 9; ++it) {
    int slot = tid + it * 256;
    if (slot < 33 * 64) {
      int c = slot >> 6;
      int kq = (slot & 63) << 2;
      float4 v = *(const float4*)&xw[(size_t)c * DI_N + k0 + kq];
      wS[c][kq] = v.x; wS[c][kq + 1] = v.y;
      wS[c][kq + 2] = v.z; wS[c][kq + 3] = v.w;
    }
  }
  __syncthreads();

  const int r = tid & 15;
  const int cg = tid >> 4;
  const int c0 = cg * 3;
  const int rc0 = c0 > 32 ? 32 : c0;
  const int rc1 = c0 + 1 > 32 ? 32 : c0 + 1;
  const int rc2 = c0 + 2 > 32 ? 32 : c0 + 2;
  float a0 = 0.f, a1 = 0.f, a2 = 0.f;
#pragma unroll 4
  for (int k = 0; k < XKCL; ++k) {
    float uv = uS[r][k];
    a0 = fmaf(uv, wS[rc0][k], a0);
    a1 = fmaf(uv, wS[rc1][k], a1);
    a2 = fmaf(uv, wS[rc2][k], a2);
  }
  size_t base = (size_t)kc * (NTOK * NPJ) + (size_t)(row0 + r) * NPJ;
  if (c0 < NPROJ)     part[base + (c0 == 0 ? 0 : c0 + 3)] = a0;
  if (c0 + 1 < NPROJ) part[base + c0 + 4] = a1;
  if (c0 + 2 < NPROJ) part[base + c0 + 5] = a2;
  if (cg == 11) {  // zero the padding slots 1..3 (deterministic, once per row)
    part[base + 1] = 0.f; part[base + 2] = 0.f; part[base + 3] = 0.f;
  }
}

// ---------------------------------------------------------------------------
// xproj stage 2: proj36 = sum over the 8 K-chunk partials (fixed order).
// ---------------------------------------------------------------------------
__global__ __launch_bounds__(256) void xproj_reduce_kernel(
    const float* __restrict__ part, float* __restrict__ proj) {
  int idx = blockIdx.x * 256 + threadIdx.x;  // < NTOK*NPJ = 147456
  float s = 0.f;
#pragma unroll
  for (int kc = 0; kc < XKC; ++kc)
    s += part[(size_t)kc * (NTOK * NPJ) + idx];
  proj[idx] = s;
}

// ---------------------------------------------------------------------------
// Scan pass 1: block = (b, chunk, 256 i-channels). proj chunk staged in LDS.
// Emits chunk-end h[16] and sdte = sum(dte) (P recomputed in fixup).
// ---------------------------------------------------------------------------
__global__ __launch_bounds__(256) void scan_pass1_kernel(
    const float* __restrict__ u2, const float* __restrict__ pj,
    const float* __restrict__ dtw, const float* __restrict__ dtb,
    const float* __restrict__ A_log,
    float* __restrict__ carryH, float* __restrict__ sdteO) {
  __shared__ float pS[CL][20];
  const int tid = threadIdx.x;
  const int bid = blockIdx.x;
  const int ib = bid & 7;
  const int c = (bid >> 3) & (NC - 1);
  const int b = bid >> 9;
  const int i = ib * 256 + tid;
  const int l0 = c * CL;
  const float LOG2E = 1.4426950408889634f;

  if (tid < CL * 5) {
    int row = tid / 5, j = tid % 5;
    float4 v = *(const float4*)&pj[((size_t)b * L_N + l0 + row) * NPJ + j * 4];
    *(float4*)&pS[row][j * 4] = v;
  }

  float A2[16];
#pragma unroll
  for (int q = 0; q < 4; ++q) {
    float4 v = *(const float4*)&A_log[i * DS_N + q * 4];
    A2[q * 4 + 0] = -__expf(v.x) * LOG2E;
    A2[q * 4 + 1] = -__expf(v.y) * LOG2E;
    A2[q * 4 + 2] = -__expf(v.z) * LOG2E;
    A2[q * 4 + 3] = -__expf(v.w) * LOG2E;
  }
  const float wl = dtw[i] * LOG2E;
  const float bl = dtb[i] * LOG2E;
  const float* un = u2 + ((size_t)b * L_N + l0) * DI_N + i;
  __syncthreads();

  float h[16] = {};
  float sdte = 0.f;
  float ucur = un[0];
#pragma unroll 2
  for (int l = 0; l < CL; ++l) {
    float unext = (l + 1 < CL) ? un[(size_t)(l + 1) * DI_N] : 0.f;
    float d0 = pS[l][0];
    float4 B0 = *(const float4*)&pS[l][4];
    float4 B1 = *(const float4*)&pS[l][8];
    float4 B2 = *(const float4*)&pS[l][12];
    float4 B3 = *(const float4*)&pS[l][16];
    float dte = 1.f + exp2f(fmaf(d0, wl, bl));
    float du = dte * ucur;
    sdte += dte;
    float Bv[16] = {B0.x, B0.y, B0.z, B0.w, B1.x, B1.y, B1.z, B1.w,
                    B2.x, B2.y, B2.z, B2.w, B3.x, B3.y, B3.z, B3.w};
#pragma unroll
    for (int s = 0; s < 16; ++s) {
      float a = exp2f(A2[s] * dte);
      h[s] = fmaf(a, h[s], Bv[s] * du);
    }
    ucur = unext;
  }
  size_t cbase = (((size_t)c * B_N + b) * DI_N + i) * DS_N;
#pragma unroll
  for (int q = 0; q < 4; ++q) {
    float4 hv = {h[q * 4], h[q * 4 + 1], h[q * 4 + 2], h[q * 4 + 3]};
    *(float4*)&carryH[cbase + q * 4] = hv;
  }
  sdteO[((size_t)c * B_N + b) * DI_N + i] = sdte;
}

// ---------------------------------------------------------------------------
// Fixup: chain chunk carries; carryH[c] <- incoming state for chunk c.
// ---------------------------------------------------------------------------
__global__ __launch_bounds__(256) void scan_fixup_kernel(
    float* __restrict__ carryH, const float* __restrict__ sdte,
    const float* __restrict__ A_log) {
  const int q = blockIdx.x * 256 + threadIdx.x;  // < B*DI*DS = 65536
  const int s = q & 15;
  const int i = (q >> 4) & (DI_N - 1);
  const float LOG2E = 1.4426950408889634f;
  const float A2 = -__expf(A_log[i * DS_N + s]) * LOG2E;
  float h = 0.f;
#pragma unroll 8
  for (int c = 0; c < NC; ++c) {
    size_t idx = (size_t)c * (B_N * DI_N * DS_N) + q;
    float Hc = carryH[idx];
    float sd = sdte[(size_t)c * (B_N * DI_N) + (q >> 4)];
    carryH[idx] = h;
    h = fmaf(exp2f(A2 * sd), h, Hc);
  }
}

// ---------------------------------------------------------------------------
// Scan pass 2: block = (b, chunk, 256 i); proj chunk in LDS; packed y out.
// ---------------------------------------------------------------------------
__global__ __launch_bounds__(256) void scan_pass2_kernel(
    const float* __restrict__ u2, const float* __restrict__ pj,
    const float* __restrict__ dtw, const float* __restrict__ dtb,
    const float* __restrict__ A_log, const float* __restrict__ Dp,
    const float* __restrict__ carryH, char* __restrict__ ypk) {
  __shared__ float pS[CL][36];
  const int tid = threadIdx.x;
  const int bid = blockIdx.x;
  const int ib = bid & 7;
  const int c = (bid >> 3) & (NC - 1);
  const int b = bid >> 9;
  const int i = ib * 256 + tid;
  const int l0 = c * CL;
  const float LOG2E = 1.4426950408889634f;

#pragma unroll
  for (int it = 0; it < 2; ++it) {
    int slot = tid + it * 256;
    if (slot < CL * 9) {
      int row = slot / 9, j = slot % 9;
      float4 v = *(const float4*)&pj[((size_t)b * L_N + l0 + row) * NPJ + j * 4];
      *(float4*)&pS[row][j * 4] = v;
    }
  }

  float A2[16];
#pragma unroll
  for (int q = 0; q < 4; ++q) {
    float4 v = *(const float4*)&A_log[i * DS_N + q * 4];
    A2[q * 4 + 0] = -__expf(v.x) * LOG2E;
    A2[q * 4 + 1] = -__expf(v.y) * LOG2E;
    A2[q * 4 + 2] = -__expf(v.z) * LOG2E;
    A2[q * 4 + 3] = -__expf(v.w) * LOG2E;
  }
  const float wl = dtw[i] * LOG2E;
  const float bl = dtb[i] * LOG2E;
  const float Dd = Dp[i];

  float h[16];
  size_t cbase = (((size_t)c * B_N + b) * DI_N + i) * DS_N;
#pragma unroll
  for (int q = 0; q < 4; ++q) {
    float4 hv = *(const float4*)&carryH[cbase + q * 4];
    h[q * 4] = hv.x; h[q * 4 + 1] = hv.y;
    h[q * 4 + 2] = hv.z; h[q * 4 + 3] = hv.w;
  }

  const float* un = u2 + ((size_t)b * L_N + l0) * DI_N + i;
  char* yb = ypk + ((size_t)b * L_N + l0) * (DI_N * 4) + (i >> 3) * 32 + (i & 7) * 2;
  __syncthreads();

  float ucur = un[0];
#pragma unroll 2
  for (int l = 0; l < CL; ++l) {
    float unext = (l + 1 < CL) ? un[(size_t)(l + 1) * DI_N] : 0.f;
    float d0 = pS[l][0];
    float4 B0 = *(const float4*)&pS[l][4];
    float4 B1 = *(const float4*)&pS[l][8];
    float4 B2 = *(const float4*)&pS[l][12];
    float4 B3 = *(const float4*)&pS[l][16];
    float4 C0 = *(const float4*)&pS[l][20];
    float4 C1 = *(const float4*)&pS[l][24];
    float4 C2 = *(const float4*)&pS[l][28];
    float4 C3 = *(const float4*)&pS[l][32];
    float dte = 1.f + exp2f(fmaf(d0, wl, bl));
    float du = dte * ucur;
    float Bv[16] = {B0.x, B0.y, B0.z, B0.w, B1.x, B1.y, B1.z, B1.w,
                    B2.x, B2.y, B2.z, B2.w, B3.x, B3.y, B3.z, B3.w};
    float Cv[16] = {C0.x, C0.y, C0.z, C0.w, C1.x, C1.y, C1.z, C1.w,
                    C2.x, C2.y, C2.z, C2.w, C3.x, C3.y, C3.z, C3.w};
    float y = Dd * ucur;
#pragma unroll
    for (int s = 0; s < 16; ++s) {
      float a = exp2f(A2[s] * dte);
      h[s] = fmaf(a, h[s], Bv[s] * du);
      y = fmaf(h[s], Cv[s], y);
    }
    unsigned short hh = f2bf_rn(y);
    char* q = yb + (size_t)l * (DI_N * 4);
    *(unsigned short*)q = hh;
    *(unsigned short*)(q + 16) = f2bf_rn(y - bf2f(hh));
    ucur = unext;
  }
}

// ---------------------------------------------------------------------------
extern "C" void kernel_launch(void* const* d_in, const int* in_sizes, int n_in,
                              void* d_out, int out_size, void* d_ws, size_t ws_size,
                              hipStream_t stream) {
  const float* x          = (const float*)d_in[0];
  const float* in_proj_w  = (const float*)d_in[1];
  const float* conv_w     = (const float*)d_in[2];
  const float* conv_b     = (const float*)d_in[3];
  const float* x_proj_w   = (const float*)d_in[4];
  const float* dt_proj_w  = (const float*)d_in[5];
  const float* dt_proj_b  = (const float*)d_in[6];
  const float* A_log      = (const float*)d_in[7];
  const float* Dp         = (const float*)d_in[8];
  const float* out_proj_w = (const float*)d_in[9];
  float* out = (float*)d_out;

  char* ws = (char*)d_ws;
  float* xz = (float*)ws;                                  // [0, 67.11MB)
  float* u2 = (float*)(ws + (size_t)NTOK * 2 * DI_N * 4);  // [67.11, 100.66)

  // packed x / in_proj_w live in the u2 region (dead until conv_silu)
  char* x_pk  = (char*)u2;                                 // 16.78MB
  char* w1_pk = x_pk + (size_t)NTOK * DM_N * 4;            // 16.78MB

  // xz region reuse after conv_silu (all within [0, 67.11MB))
  char*  y_pk   = ws;                                      // 33.55MB
  float* carryH = (float*)(ws + 33554432);                 // 16.78MB (64*2*2048*16*4)
  float* sdte   = (float*)(ws + 50331648);                 // 1.05MB  (64*2*2048*4)
  char*  w2_pk  = ws + 51380224;                           // 8.39MB
  float* xpart  = (float*)(ws + 59768832);                 // 4.72MB (8*4096*36*4)
  float* proj36 = (float*)(ws + 64487424);                 // 0.59MB (4096*36*4)

  // 1) split+pack x and in_proj_w
  {
    int n8 = NTOK * DM_N / 8;  // 524288
    split_pack_kernel<<<n8 / 256, 256, 0, stream>>>(x, (uint32_t*)x_pk, n8);
    split_pack_kernel<<<n8 / 256, 256, 0, stream>>>(in_proj_w, (uint32_t*)w1_pk, n8);
  }
  // 2) xz = x @ in_proj_w.T : M=4096 N=4096 K=1024 (K4=4096B), grid 1024
  gemm_pk_nt<<<1024, 256, 0, stream>>>(x_pk, w1_pk, xz, 2 * DI_N, DM_N * 4, 32,
                                       0, DM_N * 4, 0);
  // 3) conv + silu (float4 channels)
  conv_silu_kernel<<<(NTOK * DI_N / 4) / 256, 256, 0, stream>>>(xz, conv_w,
                                                                conv_b, u2);
  // 4) split+pack out_proj_w
  {
    int n8 = DM_N * DI_N / 8;  // 262144
    split_pack_kernel<<<n8 / 256, 256, 0, stream>>>(out_proj_w, (uint32_t*)w2_pk, n8);
  }
  // 5) proj36 = u2 @ x_proj_w.T  (2-stage K-split, padded rows)
  {
    xproj_part_kernel<<<(NTOK / 16) * XKC, 256, 0, stream>>>(u2, x_proj_w, xpart);
    xproj_reduce_kernel<<<(NTOK * NPJ) / 256, 256, 0, stream>>>(xpart, proj36);
  }
  // 6) chunked selective scan -> packed y
  {
    int nblk = B_N * NC * (DI_N / 256);  // 1024
    scan_pass1_kernel<<<nblk, 256, 0, stream>>>(u2, proj36, dt_proj_w, dt_proj_b,
                                                A_log, carryH, sdte);
    scan_fixup_kernel<<<(B_N * DI_N * DS_N) / 256, 256, 0, stream>>>(carryH, sdte,
                                                                     A_log);
    scan_pass2_kernel<<<nblk, 256, 0, stream>>>(u2, proj36, dt_proj_w, dt_proj_b,
                                                A_log, Dp, carryH, y_pk);
  }
  // 7) out = y @ out_proj_w.T : M=4096 N=1024 K=2048 (K4=8192B), grid 256
  gemm_pk_nt<<<256, 256, 0, stream>>>(y_pk, w2_pk, out, DM_N, DI_N * 4, 8,
                                      0, DI_N * 4, 0);
}

// Round 10
// 361.425 us; speedup vs baseline: 1.0279x; 1.0279x over previous
//
#include <hip/hip_runtime.h>
#include <hip/hip_bf16.h>
#include <cstddef>
#include <cstdint>

#define B_N 2
#define L_N 2048
#define DM_N 1024
#define DS_N 16
#define DI_N 2048
#define NTOK (B_N * L_N)   // 4096
#define NPROJ 33           // 2*DS+1
#define NPJ 36             // padded proj row: d0@0, B@4..19, C@20..35
#define NC 64              // scan chunks
#define CL (L_N / NC)      // 32 steps per chunk
#define XKC 8              // xproj K-split
#define XKCL (DI_N / XKC)  // 256

typedef __attribute__((ext_vector_type(8))) short short8v;
typedef __attribute__((ext_vector_type(4))) float f32x4;
typedef __attribute__((address_space(1))) void av1;
typedef __attribute__((address_space(3))) void av3;

__device__ __forceinline__ void gload16(const void* g, void* l) {
  __builtin_amdgcn_global_load_lds((av1*)g, (av3*)l, 16, 0, 0);
}

__device__ __forceinline__ unsigned short f2bf_rn(float f) {
  uint32_t u = __float_as_uint(f);
  uint32_t r = (u + 0x7fffu + ((u >> 16) & 1u)) >> 16;
  return (unsigned short)r;
}
__device__ __forceinline__ float bf2f(unsigned short h) {
  return __uint_as_float((uint32_t)h << 16);
}

// ---------------------------------------------------------------------------
// Split fp32 -> packed [row][kgroup8][16B hi | 16B lo]. 8 elements/thread.
// ---------------------------------------------------------------------------
__global__ __launch_bounds__(256) void split_pack_kernel(
    const float* __restrict__ src, uint32_t* __restrict__ dst, int n8) {
  int idx = blockIdx.x * 256 + threadIdx.x;
  if (idx >= n8) return;
  const float4* s = (const float4*)src + (size_t)idx * 2;
  float4 v0 = s[0], v1 = s[1];
  float f[8] = {v0.x, v0.y, v0.z, v0.w, v1.x, v1.y, v1.z, v1.w};
  uint32_t hi[4], lo[4];
#pragma unroll
  for (int j = 0; j < 4; ++j) {
    unsigned short h0 = f2bf_rn(f[2 * j]);
    unsigned short h1 = f2bf_rn(f[2 * j + 1]);
    unsigned short l0 = f2bf_rn(f[2 * j] - bf2f(h0));
    unsigned short l1 = f2bf_rn(f[2 * j + 1] - bf2f(h1));
    hi[j] = (uint32_t)h0 | ((uint32_t)h1 << 16);
    lo[j] = (uint32_t)l0 | ((uint32_t)l1 << 16);
  }
  uint4* d = (uint4*)dst + (size_t)idx * 2;
  d[0] = make_uint4(hi[0], hi[1], hi[2], hi[3]);
  d[1] = make_uint4(lo[0], lo[1], lo[2], lo[3]);
}

// ---------------------------------------------------------------------------
// GEMM1: packed split-bf16 NT, 128x128 tile, 4 waves (2x2), BK=32.
// LDS swizzle: phys slot p at row r holds logical p^(r&7)^((r>>3)&1);
// XOR folded into PRECOMPUTED per-chunk global source pointers (gptr[8])
// so the K-loop is pure pointer+offset (r7 addressing, r9 conflict-freedom).
// ---------------------------------------------------------------------------
__global__ __launch_bounds__(256) void gemm_pk_nt(
    const char* __restrict__ Apk, const char* __restrict__ Bpk,
    float* __restrict__ C, int N, int K4, int gx) {
  __shared__ __align__(16) char lds[32768];
  const int tid = threadIdx.x;
  const int lane = tid & 63;
  const int wave = tid >> 6;

  const int nwg = gridDim.x;
  const int cpx = nwg >> 3;
  const int bid = blockIdx.x;
  const int wg = (bid & 7) * cpx + (bid >> 3);
  const int bx = wg % gx;
  const int by = wg / gx;
  const int m0 = by * 128, n0 = bx * 128;

  const int wr = wave >> 1, wc = wave & 1;

  const char* gbase = (wave & 2) ? Bpk : Apk;
  const int rowbase = ((wave & 2) ? n0 : m0) + (wave & 1) * 64;
  const int rloc = lane >> 3;
  const int sslot = (lane & 7) ^ rloc;
  const char* gsrc = gbase + (size_t)(rowbase + rloc) * K4 + sslot * 16;
  const size_t rstride = (size_t)8 * K4;
  const char* gptr[8];
#pragma unroll
  for (int c = 0; c < 8; ++c)
    gptr[c] = (const char*)((uintptr_t)(gsrc + c * rstride) ^ ((c & 1) << 4));
  char* ldst = lds + wave * 8192 + lane * 16;

  f32x4 acc[4][4] = {};
  const int fr = lane & 15;
  const int fg = lane >> 4;
  const int sA = ((fg * 2) ^ (fr & 7) ^ ((fr >> 3) & 1)) * 16;
  const int abase = (wr * 64 + fr) * 128 + sA;
  const int bbase = 16384 + (wc * 64 + fr) * 128 + sA;

  for (int kt4 = 0; kt4 < K4; kt4 += 128) {
#pragma unroll
    for (int c = 0; c < 8; ++c)
      gload16(gptr[c] + kt4, ldst + c * 1024);
    __syncthreads();

    short8v afh[4], afl[4], bfh[4], bfl[4];
#pragma unroll
    for (int m = 0; m < 4; ++m) {
      int a = abase + m * 2048;
      afh[m] = *(const short8v*)(lds + a);
      afl[m] = *(const short8v*)(lds + (a ^ 16));
    }
#pragma unroll
    for (int n = 0; n < 4; ++n) {
      int b = bbase + n * 2048;
      bfh[n] = *(const short8v*)(lds + b);
      bfl[n] = *(const short8v*)(lds + (b ^ 16));
    }
#pragma unroll
    for (int m = 0; m < 4; ++m) {
#pragma unroll
      for (int n = 0; n < 4; ++n) {
        asm("v_mfma_f32_16x16x32_bf16 %0, %1, %2, %0"
            : "+v"(acc[m][n]) : "v"(afh[m]), "v"(bfh[n]));
        asm("v_mfma_f32_16x16x32_bf16 %0, %1, %2, %0"
            : "+v"(acc[m][n]) : "v"(afh[m]), "v"(bfl[n]));
        asm("v_mfma_f32_16x16x32_bf16 %0, %1, %2, %0"
            : "+v"(acc[m][n]) : "v"(afl[m]), "v"(bfh[n]));
      }
    }
    __syncthreads();
  }

#pragma unroll
  for (int m = 0; m < 4; ++m) {
#pragma unroll
    for (int n = 0; n < 4; ++n) {
#pragma unroll
      for (int q = 0; q < 4; ++q) {
        int row = m0 + wr * 64 + m * 16 + fg * 4 + q;
        int col = n0 + wc * 64 + n * 16 + fr;
        C[(size_t)row * N + col] = acc[m][n][q];
      }
    }
  }
}

// ---------------------------------------------------------------------------
// GEMM2: out = y @ w2^T, M=4096 N=1024 K=2048. Tile 64M x 128N, grid 512
// (2 blocks/CU), 4 waves each 64x32 (acc[4][2]). LDS 24KB: A 8KB + B 16KB.
// Same packed layout and swizzle algebra as GEMM1. XCD mapping: each XCD
// owns one 128-col B panel (1MB, L2-resident) and streams A.
// ---------------------------------------------------------------------------
__global__ __launch_bounds__(256) void gemm2_pk_nt(
    const char* __restrict__ Apk, const char* __restrict__ Bpk,
    float* __restrict__ C) {
  __shared__ __align__(16) char lds[24576];
  const int tid = threadIdx.x;
  const int lane = tid & 63;
  const int wave = tid >> 6;
  const int K4 = DI_N * 4;  // 8192 bytes per packed row

  const int bid = blockIdx.x;                 // 512 blocks
  const int wg = (bid & 7) * 64 + (bid >> 3); // XCD x -> wg in [64x, 64x+64)
  const int bx = wg >> 6;                     // 0..7  (B panel, fixed per XCD)
  const int by = wg & 63;                     // 0..63 (A stripe)
  const int m0 = by * 64, n0 = bx * 128;

  // Staging: 1536 slots of 16B (A rows 0..63 = slots 0..511, B rows 0..127
  // = slots 512..1535), 6 chunks of 256 slots; dst = lds + slot*16 (linear).
  const char* gptr[6];
#pragma unroll
  for (int c = 0; c < 6; ++c) {
    int s = c * 256 + tid;
    int isB = (s >= 512) ? 1 : 0;
    int t = s - isB * 512;
    int r = t >> 3;
    int sl = (t & 7) ^ (r & 7) ^ ((r >> 3) & 1);
    const char* base = isB ? (Bpk + (size_t)(n0 + r) * K4)
                           : (Apk + (size_t)(m0 + r) * K4);
    gptr[c] = base + sl * 16;
  }
  char* ldst = lds + tid * 16;  // chunk c adds c*4096

  f32x4 acc[4][2] = {};
  const int fr = lane & 15;
  const int fg = lane >> 4;
  const int sA = ((fg * 2) ^ (fr & 7) ^ ((fr >> 3) & 1)) * 16;
  const int abase0 = fr * 128 + sA;                       // A region at 0
  const int bbase0 = 8192 + (wave * 32 + fr) * 128 + sA;  // B region at 8KB

  for (int kt4 = 0; kt4 < K4; kt4 += 128) {
#pragma unroll
    for (int c = 0; c < 6; ++c)
      gload16(gptr[c] + kt4, ldst + c * 4096);
    __syncthreads();

    short8v afh[4], afl[4], bfh[2], bfl[2];
#pragma unroll
    for (int m = 0; m < 4; ++m) {
      int a = abase0 + m * 2048;
      afh[m] = *(const short8v*)(lds + a);
      afl[m] = *(const short8v*)(lds + (a ^ 16));
    }
#pragma unroll
    for (int n = 0; n < 2; ++n) {
      int b = bbase0 + n * 2048;
      bfh[n] = *(const short8v*)(lds + b);
      bfl[n] = *(const short8v*)(lds + (b ^ 16));
    }
#pragma unroll
    for (int m = 0; m < 4; ++m) {
#pragma unroll
      for (int n = 0; n < 2; ++n) {
        asm("v_mfma_f32_16x16x32_bf16 %0, %1, %2, %0"
            : "+v"(acc[m][n]) : "v"(afh[m]), "v"(bfh[n]));
        asm("v_mfma_f32_16x16x32_bf16 %0, %1, %2, %0"
            : "+v"(acc[m][n]) : "v"(afh[m]), "v"(bfl[n]));
        asm("v_mfma_f32_16x16x32_bf16 %0, %1, %2, %0"
            : "+v"(acc[m][n]) : "v"(afl[m]), "v"(bfh[n]));
      }
    }
    __syncthreads();
  }

#pragma unroll
  for (int m = 0; m < 4; ++m) {
#pragma unroll
    for (int n = 0; n < 2; ++n) {
#pragma unroll
      for (int q = 0; q < 4; ++q) {
        int row = m0 + m * 16 + fg * 4 + q;
        int col = n0 + wave * 32 + n * 16 + fr;
        C[(size_t)row * DM_N + col] = acc[m][n][q];
      }
    }
  }
}

// ---------------------------------------------------------------------------
// Depthwise causal conv (DC=4) + bias, times silu(z). float4 over channels.
// ---------------------------------------------------------------------------
__global__ __launch_bounds__(256) void conv_silu_kernel(
    const float* __restrict__ xz, const float* __restrict__ cw,
    const float* __restrict__ cb, float* __restrict__ u2) {
  int idx = blockIdx.x * 256 + threadIdx.x;  // < NTOK*DI/4 = 2097152
  int i4 = idx & (DI_N / 4 - 1);
  int n = idx >> 9;
  int i = i4 << 2;
  int l = n & (L_N - 1);
  const float* base = xz + (size_t)n * (2 * DI_N) + i;
  float4 zero = {0.f, 0.f, 0.f, 0.f};
  float4 u0 = *(const float4*)base;
  float4 u1 = (l >= 1) ? *(const float4*)(base - 2 * DI_N) : zero;
  float4 um2 = (l >= 2) ? *(const float4*)(base - 4 * DI_N) : zero;
  float4 um3 = (l >= 3) ? *(const float4*)(base - 6 * DI_N) : zero;
  float4 z = *(const float4*)(base + DI_N);
  float4 bia = *(const float4*)&cb[i];
  float4 w0 = *(const float4*)&cw[i * 4];
  float4 w1 = *(const float4*)&cw[i * 4 + 4];
  float4 w2 = *(const float4*)&cw[i * 4 + 8];
  float4 w3 = *(const float4*)&cw[i * 4 + 12];
  float4 r;
  r.x = fmaf(w0.w, u0.x, fmaf(w0.z, u1.x, fmaf(w0.y, um2.x, fmaf(w0.x, um3.x, bia.x))));
  r.y = fmaf(w1.w, u0.y, fmaf(w1.z, u1.y, fmaf(w1.y, um2.y, fmaf(w1.x, um3.y, bia.y))));
  r.z = fmaf(w2.w, u0.z, fmaf(w2.z, u1.z, fmaf(w2.y, um2.z, fmaf(w2.x, um3.z, bia.z))));
  r.w = fmaf(w3.w, u0.w, fmaf(w3.z, u1.w, fmaf(w3.y, um2.w, fmaf(w3.x, um3.w, bia.w))));
  r.x *= z.x / (1.f + __expf(-z.x));
  r.y *= z.y / (1.f + __expf(-z.y));
  r.z *= z.z / (1.f + __expf(-z.z));
  r.w *= z.w / (1.f + __expf(-z.w));
  *(float4*)&u2[(size_t)n * DI_N + i] = r;
}

// ---------------------------------------------------------------------------
// xproj stage 1: partials into padded 36-wide rows (d0@0, B@4..19, C@20..35).
// ---------------------------------------------------------------------------
__global__ __launch_bounds__(256) void xproj_part_kernel(
    const float* __restrict__ u2, const float* __restrict__ xw,
    float* __restrict__ part) {
  __shared__ float uS[16][257];
  __shared__ float wS[33][257];
  const int tid = threadIdx.x;
  const int kc = blockIdx.x & (XKC - 1);
  const int rb = blockIdx.x >> 3;
  const int row0 = rb * 16;
  const int k0 = kc * XKCL;

#pragma unroll
  for (int it = 0; it < 4; ++it) {
    int slot = tid + it * 256;
    int r = slot >> 6;
    int kq = (slot & 63) << 2;
    float4 v = *(const float4*)&u2[(size_t)(row0 + r) * DI_N + k0 + kq];
    uS[r][kq] = v.x; uS[r][kq + 1] = v.y;
    uS[r][kq + 2] = v.z; uS[r][kq + 3] = v.w;
  }
#pragma unroll
  for (int it = 0; it < 9; ++it) {
    int slot = tid + it * 256;
    if (slot < 33 * 64) {
      int c = slot >> 6;
      int kq = (slot & 63) << 2;
      float4 v = *(const float4*)&xw[(size_t)c * DI_N + k0 + kq];
      wS[c][kq] = v.x; wS[c][kq + 1] = v.y;
      wS[c][kq + 2] = v.z; wS[c][kq + 3] = v.w;
    }
  }
  __syncthreads();

  const int r = tid & 15;
  const int cg = tid >> 4;
  const int c0 = cg * 3;
  const int rc0 = c0 > 32 ? 32 : c0;
  const int rc1 = c0 + 1 > 32 ? 32 : c0 + 1;
  const int rc2 = c0 + 2 > 32 ? 32 : c0 + 2;
  float a0 = 0.f, a1 = 0.f, a2 = 0.f;
#pragma unroll 4
  for (int k = 0; k < XKCL; ++k) {
    float uv = uS[r][k];
    a0 = fmaf(uv, wS[rc0][k], a0);
    a1 = fmaf(uv, wS[rc1][k], a1);
    a2 = fmaf(uv, wS[rc2][k], a2);
  }
  size_t base = (size_t)kc * (NTOK * NPJ) + (size_t)(row0 + r) * NPJ;
  if (c0 < NPROJ)     part[base + (c0 == 0 ? 0 : c0 + 3)] = a0;
  if (c0 + 1 < NPROJ) part[base + c0 + 4] = a1;
  if (c0 + 2 < NPROJ) part[base + c0 + 5] = a2;
  if (cg == 11) {  // zero the padding slots 1..3 (deterministic)
    part[base + 1] = 0.f; part[base + 2] = 0.f; part[base + 3] = 0.f;
  }
}

// ---------------------------------------------------------------------------
// xproj stage 2: proj36 = sum over the 8 K-chunk partials (fixed order).
// ---------------------------------------------------------------------------
__global__ __launch_bounds__(256) void xproj_reduce_kernel(
    const float* __restrict__ part, float* __restrict__ proj) {
  int idx = blockIdx.x * 256 + threadIdx.x;  // < NTOK*NPJ = 147456
  float s = 0.f;
#pragma unroll
  for (int kc = 0; kc < XKC; ++kc)
    s += part[(size_t)kc * (NTOK * NPJ) + idx];
  proj[idx] = s;
}

// ---------------------------------------------------------------------------
// Scan pass 1: block = (b, chunk, 256 i-channels). proj chunk staged in LDS.
// ---------------------------------------------------------------------------
__global__ __launch_bounds__(256) void scan_pass1_kernel(
    const float* __restrict__ u2, const float* __restrict__ pj,
    const float* __restrict__ dtw, const float* __restrict__ dtb,
    const float* __restrict__ A_log,
    float* __restrict__ carryH, float* __restrict__ sdteO) {
  __shared__ float pS[CL][20];
  const int tid = threadIdx.x;
  const int bid = blockIdx.x;
  const int ib = bid & 7;
  const int c = (bid >> 3) & (NC - 1);
  const int b = bid >> 9;
  const int i = ib * 256 + tid;
  const int l0 = c * CL;
  const float LOG2E = 1.4426950408889634f;

  if (tid < CL * 5) {
    int row = tid / 5, j = tid % 5;
    float4 v = *(const float4*)&pj[((size_t)b * L_N + l0 + row) * NPJ + j * 4];
    *(float4*)&pS[row][j * 4] = v;
  }

  float A2[16];
#pragma unroll
  for (int q = 0; q < 4; ++q) {
    float4 v = *(const float4*)&A_log[i * DS_N + q * 4];
    A2[q * 4 + 0] = -__expf(v.x) * LOG2E;
    A2[q * 4 + 1] = -__expf(v.y) * LOG2E;
    A2[q * 4 + 2] = -__expf(v.z) * LOG2E;
    A2[q * 4 + 3] = -__expf(v.w) * LOG2E;
  }
  const float wl = dtw[i] * LOG2E;
  const float bl = dtb[i] * LOG2E;
  const float* un = u2 + ((size_t)b * L_N + l0) * DI_N + i;
  __syncthreads();

  float h[16] = {};
  float sdte = 0.f;
  float ucur = un[0];
#pragma unroll 2
  for (int l = 0; l < CL; ++l) {
    float unext = (l + 1 < CL) ? un[(size_t)(l + 1) * DI_N] : 0.f;
    float d0 = pS[l][0];
    float4 B0 = *(const float4*)&pS[l][4];
    float4 B1 = *(const float4*)&pS[l][8];
    float4 B2 = *(const float4*)&pS[l][12];
    float4 B3 = *(const float4*)&pS[l][16];
    float dte = 1.f + exp2f(fmaf(d0, wl, bl));
    float du = dte * ucur;
    sdte += dte;
    float Bv[16] = {B0.x, B0.y, B0.z, B0.w, B1.x, B1.y, B1.z, B1.w,
                    B2.x, B2.y, B2.z, B2.w, B3.x, B3.y, B3.z, B3.w};
#pragma unroll
    for (int s = 0; s < 16; ++s) {
      float a = exp2f(A2[s] * dte);
      h[s] = fmaf(a, h[s], Bv[s] * du);
    }
    ucur = unext;
  }
  size_t cbase = (((size_t)c * B_N + b) * DI_N + i) * DS_N;
#pragma unroll
  for (int q = 0; q < 4; ++q) {
    float4 hv = {h[q * 4], h[q * 4 + 1], h[q * 4 + 2], h[q * 4 + 3]};
    *(float4*)&carryH[cbase + q * 4] = hv;
  }
  sdteO[((size_t)c * B_N + b) * DI_N + i] = sdte;
}

// ---------------------------------------------------------------------------
// Fixup: chain chunk carries; carryH[c] <- incoming state for chunk c.
// ---------------------------------------------------------------------------
__global__ __launch_bounds__(256) void scan_fixup_kernel(
    float* __restrict__ carryH, const float* __restrict__ sdte,
    const float* __restrict__ A_log) {
  const int q = blockIdx.x * 256 + threadIdx.x;  // < B*DI*DS = 65536
  const int s = q & 15;
  const int i = (q >> 4) & (DI_N - 1);
  const float LOG2E = 1.4426950408889634f;
  const float A2 = -__expf(A_log[i * DS_N + s]) * LOG2E;
  float h = 0.f;
#pragma unroll 8
  for (int c = 0; c < NC; ++c) {
    size_t idx = (size_t)c * (B_N * DI_N * DS_N) + q;
    float Hc = carryH[idx];
    float sd = sdte[(size_t)c * (B_N * DI_N) + (q >> 4)];
    carryH[idx] = h;
    h = fmaf(exp2f(A2 * sd), h, Hc);
  }
}

// ---------------------------------------------------------------------------
// Scan pass 2: block = (b, chunk, 256 i); proj chunk in LDS; packed y out.
// ---------------------------------------------------------------------------
__global__ __launch_bounds__(256) void scan_pass2_kernel(
    const float* __restrict__ u2, const float* __restrict__ pj,
    const float* __restrict__ dtw, const float* __restrict__ dtb,
    const float* __restrict__ A_log, const float* __restrict__ Dp,
    const float* __restrict__ carryH, char* __restrict__ ypk) {
  __shared__ float pS[CL][36];
  const int tid = threadIdx.x;
  const int bid = blockIdx.x;
  const int ib = bid & 7;
  const int c = (bid >> 3) & (NC - 1);
  const int b = bid >> 9;
  const int i = ib * 256 + tid;
  const int l0 = c * CL;
  const float LOG2E = 1.4426950408889634f;

#pragma unroll
  for (int it = 0; it < 2; ++it) {
    int slot = tid + it * 256;
    if (slot < CL * 9) {
      int row = slot / 9, j = slot % 9;
      float4 v = *(const float4*)&pj[((size_t)b * L_N + l0 + row) * NPJ + j * 4];
      *(float4*)&pS[row][j * 4] = v;
    }
  }

  float A2[16];
#pragma unroll
  for (int q = 0; q < 4; ++q) {
    float4 v = *(const float4*)&A_log[i * DS_N + q * 4];
    A2[q * 4 + 0] = -__expf(v.x) * LOG2E;
    A2[q * 4 + 1] = -__expf(v.y) * LOG2E;
    A2[q * 4 + 2] = -__expf(v.z) * LOG2E;
    A2[q * 4 + 3] = -__expf(v.w) * LOG2E;
  }
  const float wl = dtw[i] * LOG2E;
  const float bl = dtb[i] * LOG2E;
  const float Dd = Dp[i];

  float h[16];
  size_t cbase = (((size_t)c * B_N + b) * DI_N + i) * DS_N;
#pragma unroll
  for (int q = 0; q < 4; ++q) {
    float4 hv = *(const float4*)&carryH[cbase + q * 4];
    h[q * 4] = hv.x; h[q * 4 + 1] = hv.y;
    h[q * 4 + 2] = hv.z; h[q * 4 + 3] = hv.w;
  }

  const float* un = u2 + ((size_t)b * L_N + l0) * DI_N + i;
  char* yb = ypk + ((size_t)b * L_N + l0) * (DI_N * 4) + (i >> 3) * 32 + (i & 7) * 2;
  __syncthreads();

  float ucur = un[0];
#pragma unroll 2
  for (int l = 0; l < CL; ++l) {
    float unext = (l + 1 < CL) ? un[(size_t)(l + 1) * DI_N] : 0.f;
    float d0 = pS[l][0];
    float4 B0 = *(const float4*)&pS[l][4];
    float4 B1 = *(const float4*)&pS[l][8];
    float4 B2 = *(const float4*)&pS[l][12];
    float4 B3 = *(const float4*)&pS[l][16];
    float4 C0 = *(const float4*)&pS[l][20];
    float4 C1 = *(const float4*)&pS[l][24];
    float4 C2 = *(const float4*)&pS[l][28];
    float4 C3 = *(const float4*)&pS[l][32];
    float dte = 1.f + exp2f(fmaf(d0, wl, bl));
    float du = dte * ucur;
    float Bv[16] = {B0.x, B0.y, B0.z, B0.w, B1.x, B1.y, B1.z, B1.w,
                    B2.x, B2.y, B2.z, B2.w, B3.x, B3.y, B3.z, B3.w};
    float Cv[16] = {C0.x, C0.y, C0.z, C0.w, C1.x, C1.y, C1.z, C1.w,
                    C2.x, C2.y, C2.z, C2.w, C3.x, C3.y, C3.z, C3.w};
    float y = Dd * ucur;
#pragma unroll
    for (int s = 0; s < 16; ++s) {
      float a = exp2f(A2[s] * dte);
      h[s] = fmaf(a, h[s], Bv[s] * du);
      y = fmaf(h[s], Cv[s], y);
    }
    unsigned short hh = f2bf_rn(y);
    char* q = yb + (size_t)l * (DI_N * 4);
    *(unsigned short*)q = hh;
    *(unsigned short*)(q + 16) = f2bf_rn(y - bf2f(hh));
    ucur = unext;
  }
}

// ---------------------------------------------------------------------------
extern "C" void kernel_launch(void* const* d_in, const int* in_sizes, int n_in,
                              void* d_out, int out_size, void* d_ws, size_t ws_size,
                              hipStream_t stream) {
  const float* x          = (const float*)d_in[0];
  const float* in_proj_w  = (const float*)d_in[1];
  const float* conv_w     = (const float*)d_in[2];
  const float* conv_b     = (const float*)d_in[3];
  const float* x_proj_w   = (const float*)d_in[4];
  const float* dt_proj_w  = (const float*)d_in[5];
  const float* dt_proj_b  = (const float*)d_in[6];
  const float* A_log      = (const float*)d_in[7];
  const float* Dp         = (const float*)d_in[8];
  const float* out_proj_w = (const float*)d_in[9];
  float* out = (float*)d_out;

  char* ws = (char*)d_ws;
  float* xz = (float*)ws;                                  // [0, 67.11MB)
  float* u2 = (float*)(ws + (size_t)NTOK * 2 * DI_N * 4);  // [67.11, 100.66)

  // packed x / in_proj_w live in the u2 region (dead until conv_silu)
  char* x_pk  = (char*)u2;                                 // 16.78MB
  char* w1_pk = x_pk + (size_t)NTOK * DM_N * 4;            // 16.78MB

  // xz region reuse after conv_silu (all within [0, 67.11MB))
  char*  y_pk   = ws;                                      // 33.55MB
  float* carryH = (float*)(ws + 33554432);                 // 16.78MB
  float* sdte   = (float*)(ws + 50331648);                 // 1.05MB
  char*  w2_pk  = ws + 51380224;                           // 8.39MB
  float* xpart  = (float*)(ws + 59768832);                 // 4.72MB
  float* proj36 = (float*)(ws + 64487424);                 // 0.59MB

  // 1) split+pack x and in_proj_w
  {
    int n8 = NTOK * DM_N / 8;  // 524288
    split_pack_kernel<<<n8 / 256, 256, 0, stream>>>(x, (uint32_t*)x_pk, n8);
    split_pack_kernel<<<n8 / 256, 256, 0, stream>>>(in_proj_w, (uint32_t*)w1_pk, n8);
  }
  // 2) xz = x @ in_proj_w.T : M=4096 N=4096 K=1024, grid 1024
  gemm_pk_nt<<<1024, 256, 0, stream>>>(x_pk, w1_pk, xz, 2 * DI_N, DM_N * 4, 32);
  // 3) conv + silu (float4 channels)
  conv_silu_kernel<<<(NTOK * DI_N / 4) / 256, 256, 0, stream>>>(xz, conv_w,
                                                                conv_b, u2);
  // 4) split+pack out_proj_w
  {
    int n8 = DM_N * DI_N / 8;  // 262144
    split_pack_kernel<<<n8 / 256, 256, 0, stream>>>(out_proj_w, (uint32_t*)w2_pk, n8);
  }
  // 5) proj36 = u2 @ x_proj_w.T  (2-stage K-split, padded rows)
  {
    xproj_part_kernel<<<(NTOK / 16) * XKC, 256, 0, stream>>>(u2, x_proj_w, xpart);
    xproj_reduce_kernel<<<(NTOK * NPJ) / 256, 256, 0, stream>>>(xpart, proj36);
  }
  // 6) chunked selective scan -> packed y
  {
    int nblk = B_N * NC * (DI_N / 256);  // 1024
    scan_pass1_kernel<<<nblk, 256, 0, stream>>>(u2, proj36, dt_proj_w, dt_proj_b,
                                                A_log, carryH, sdte);
    scan_fixup_kernel<<<(B_N * DI_N * DS_N) / 256, 256, 0, stream>>>(carryH, sdte,
                                                                     A_log);
    scan_pass2_kernel<<<nblk, 256, 0, stream>>>(u2, proj36, dt_proj_w, dt_proj_b,
                                                A_log, Dp, carryH, y_pk);
  }
  // 7) out = y @ out_proj_w.T : M=4096 N=1024 K=2048, tile 64x128, grid 512
  gemm2_pk_nt<<<512, 256, 0, stream>>>(y_pk, w2_pk, out);
}

// Round 11
// 354.720 us; speedup vs baseline: 1.0473x; 1.0189x over previous
//
#include <hip/hip_runtime.h>
#include <hip/hip_bf16.h>
#include <cstddef>
#include <cstdint>

#define B_N 2
#define L_N 2048
#define DM_N 1024
#define DS_N 16
#define DI_N 2048
#define NTOK (B_N * L_N)   // 4096
#define NPROJ 33           // 2*DS+1
#define NPJ 36             // padded proj row: d0@0, B@4..19, C@20..35
#define NC 64              // scan chunks
#define CL (L_N / NC)      // 32 steps per chunk
#define XKC 8              // xproj K-split
#define XKCL (DI_N / XKC)  // 256

typedef __attribute__((ext_vector_type(8))) short short8v;
typedef __attribute__((ext_vector_type(4))) float f32x4;
typedef __attribute__((address_space(1))) void av1;
typedef __attribute__((address_space(3))) void av3;

__device__ __forceinline__ void gload16(const void* g, void* l) {
  __builtin_amdgcn_global_load_lds((av1*)g, (av3*)l, 16, 0, 0);
}

__device__ __forceinline__ unsigned short f2bf_rn(float f) {
  uint32_t u = __float_as_uint(f);
  uint32_t r = (u + 0x7fffu + ((u >> 16) & 1u)) >> 16;
  return (unsigned short)r;
}
__device__ __forceinline__ float bf2f(unsigned short h) {
  return __uint_as_float((uint32_t)h << 16);
}

// ---------------------------------------------------------------------------
// Split fp32 -> packed [row][kgroup8][16B hi | 16B lo]. 8 elements/thread.
// ---------------------------------------------------------------------------
__global__ __launch_bounds__(256) void split_pack_kernel(
    const float* __restrict__ src, uint32_t* __restrict__ dst, int n8) {
  int idx = blockIdx.x * 256 + threadIdx.x;
  if (idx >= n8) return;
  const float4* s = (const float4*)src + (size_t)idx * 2;
  float4 v0 = s[0], v1 = s[1];
  float f[8] = {v0.x, v0.y, v0.z, v0.w, v1.x, v1.y, v1.z, v1.w};
  uint32_t hi[4], lo[4];
#pragma unroll
  for (int j = 0; j < 4; ++j) {
    unsigned short h0 = f2bf_rn(f[2 * j]);
    unsigned short h1 = f2bf_rn(f[2 * j + 1]);
    unsigned short l0 = f2bf_rn(f[2 * j] - bf2f(h0));
    unsigned short l1 = f2bf_rn(f[2 * j + 1] - bf2f(h1));
    hi[j] = (uint32_t)h0 | ((uint32_t)h1 << 16);
    lo[j] = (uint32_t)l0 | ((uint32_t)l1 << 16);
  }
  uint4* d = (uint4*)dst + (size_t)idx * 2;
  d[0] = make_uint4(hi[0], hi[1], hi[2], hi[3]);
  d[1] = make_uint4(lo[0], lo[1], lo[2], lo[3]);
}

// ---------------------------------------------------------------------------
// GEMM1: packed split-bf16 NT, 128x128 tile, 4 waves (2x2), BK=32.
// r6-form addressing (measured best: VGPR 64, 89.6us): single base pointer,
// uniform chunk stride, slot XOR (lane&7)^rloc on staging + (fg*2)^(fr&7) on
// read. ~8.4M 2-4 way LDS conflicts accepted (hidden under MFMA; the
// conflict-free variant costs 20 VGPR -> occupancy loss, measured slower).
// ---------------------------------------------------------------------------
__global__ __launch_bounds__(256) void gemm_pk_nt(
    const char* __restrict__ Apk, const char* __restrict__ Bpk,
    float* __restrict__ C, int N, int K4, int gx) {
  __shared__ __align__(16) char lds[32768];
  const int tid = threadIdx.x;
  const int lane = tid & 63;
  const int wave = tid >> 6;

  const int nwg = gridDim.x;
  const int cpx = nwg >> 3;
  const int bid = blockIdx.x;
  const int wg = (bid & 7) * cpx + (bid >> 3);
  const int bx = wg % gx;
  const int by = wg / gx;
  const int m0 = by * 128, n0 = bx * 128;

  const int wr = wave >> 1, wc = wave & 1;

  const char* gbase = (wave & 2) ? Bpk : Apk;
  const int rowbase = ((wave & 2) ? n0 : m0) + (wave & 1) * 64;
  const int rloc = lane >> 3;
  const int sslot = (lane & 7) ^ rloc;
  const char* gsrc = gbase + (size_t)(rowbase + rloc) * K4 + sslot * 16;
  const size_t cstride = (size_t)8 * K4;
  char* ldst = lds + wave * 8192 + lane * 16;

  f32x4 acc[4][4] = {};
  const int fr = lane & 15;
  const int fg = lane >> 4;
  const int sA = ((fg * 2) ^ (fr & 7)) * 16;
  const int abase = (wr * 64 + fr) * 128 + sA;
  const int bbase = 16384 + (wc * 64 + fr) * 128 + sA;

  for (int kt4 = 0; kt4 < K4; kt4 += 128) {
#pragma unroll
    for (int c = 0; c < 8; ++c)
      gload16(gsrc + c * cstride + kt4, ldst + c * 1024);
    __syncthreads();

    short8v afh[4], afl[4], bfh[4], bfl[4];
#pragma unroll
    for (int m = 0; m < 4; ++m) {
      int a = abase + m * 2048;
      afh[m] = *(const short8v*)(lds + a);
      afl[m] = *(const short8v*)(lds + (a ^ 16));
    }
#pragma unroll
    for (int n = 0; n < 4; ++n) {
      int b = bbase + n * 2048;
      bfh[n] = *(const short8v*)(lds + b);
      bfl[n] = *(const short8v*)(lds + (b ^ 16));
    }
#pragma unroll
    for (int m = 0; m < 4; ++m) {
#pragma unroll
      for (int n = 0; n < 4; ++n) {
        asm("v_mfma_f32_16x16x32_bf16 %0, %1, %2, %0"
            : "+v"(acc[m][n]) : "v"(afh[m]), "v"(bfh[n]));
        asm("v_mfma_f32_16x16x32_bf16 %0, %1, %2, %0"
            : "+v"(acc[m][n]) : "v"(afh[m]), "v"(bfl[n]));
        asm("v_mfma_f32_16x16x32_bf16 %0, %1, %2, %0"
            : "+v"(acc[m][n]) : "v"(afl[m]), "v"(bfh[n]));
      }
    }
    __syncthreads();
  }

#pragma unroll
  for (int m = 0; m < 4; ++m) {
#pragma unroll
    for (int n = 0; n < 4; ++n) {
#pragma unroll
      for (int q = 0; q < 4; ++q) {
        int row = m0 + wr * 64 + m * 16 + fg * 4 + q;
        int col = n0 + wc * 64 + n * 16 + fr;
        C[(size_t)row * N + col] = acc[m][n][q];
      }
    }
  }
}

// ---------------------------------------------------------------------------
// GEMM2: out = y @ w2^T, M=4096 N=1024 K=2048. Tile 64M x 128N, grid 512
// (2 blocks/CU), 4 waves each 64x32 (acc[4][2]). LDS 24KB: A 8KB + B 16KB.
// r6-form addressing: two base pointers (A,B) + uniform 32*K4 chunk stride.
// XCD mapping: each XCD owns one 128-col B panel (1MB, L2-resident).
// ---------------------------------------------------------------------------
__global__ __launch_bounds__(256) void gemm2_pk_nt(
    const char* __restrict__ Apk, const char* __restrict__ Bpk,
    float* __restrict__ C) {
  __shared__ __align__(16) char lds[24576];
  const int tid = threadIdx.x;
  const int lane = tid & 63;
  const int wave = tid >> 6;
  const int K4 = DI_N * 4;  // 8192 bytes per packed row

  const int bid = blockIdx.x;                 // 512 blocks
  const int wg = (bid & 7) * 64 + (bid >> 3); // XCD x -> wg in [64x, 64x+64)
  const int bx = wg >> 6;                     // 0..7  (B panel, fixed per XCD)
  const int by = wg & 63;                     // 0..63 (A stripe)
  const int m0 = by * 64, n0 = bx * 128;

  // Staging: chunk c writes slots [c*256+tid]. A = slots 0..511 (rows 0..63),
  // B = slots 512..1535 (rows 0..127). Row r = chunkrow*32 + (tid>>3);
  // slot-in-row = (tid&7) XOR'd by (r&7) == (tid>>3)&7 (uniform across chunks).
  const int rloc = tid >> 3;                        // 0..31
  const int sl = (tid & 7) ^ (rloc & 7);
  const char* gA = Apk + (size_t)(m0 + rloc) * K4 + sl * 16;
  const char* gB = Bpk + (size_t)(n0 + rloc) * K4 + sl * 16;
  const size_t cs = (size_t)32 * K4;
  char* ldst = lds + tid * 16;

  f32x4 acc[4][2] = {};
  const int fr = lane & 15;
  const int fg = lane >> 4;
  const int sA = ((fg * 2) ^ (fr & 7)) * 16;
  const int abase0 = fr * 128 + sA;                       // A region at 0
  const int bbase0 = 8192 + (wave * 32 + fr) * 128 + sA;  // B region at 8KB

  for (int kt4 = 0; kt4 < K4; kt4 += 128) {
    gload16(gA + kt4, ldst);
    gload16(gA + cs + kt4, ldst + 4096);
    gload16(gB + kt4, ldst + 8192);
    gload16(gB + cs + kt4, ldst + 12288);
    gload16(gB + 2 * cs + kt4, ldst + 16384);
    gload16(gB + 3 * cs + kt4, ldst + 20480);
    __syncthreads();

    short8v afh[4], afl[4], bfh[2], bfl[2];
#pragma unroll
    for (int m = 0; m < 4; ++m) {
      int a = abase0 + m * 2048;
      afh[m] = *(const short8v*)(lds + a);
      afl[m] = *(const short8v*)(lds + (a ^ 16));
    }
#pragma unroll
    for (int n = 0; n < 2; ++n) {
      int b = bbase0 + n * 2048;
      bfh[n] = *(const short8v*)(lds + b);
      bfl[n] = *(const short8v*)(lds + (b ^ 16));
    }
#pragma unroll
    for (int m = 0; m < 4; ++m) {
#pragma unroll
      for (int n = 0; n < 2; ++n) {
        asm("v_mfma_f32_16x16x32_bf16 %0, %1, %2, %0"
            : "+v"(acc[m][n]) : "v"(afh[m]), "v"(bfh[n]));
        asm("v_mfma_f32_16x16x32_bf16 %0, %1, %2, %0"
            : "+v"(acc[m][n]) : "v"(afh[m]), "v"(bfl[n]));
        asm("v_mfma_f32_16x16x32_bf16 %0, %1, %2, %0"
            : "+v"(acc[m][n]) : "v"(afl[m]), "v"(bfh[n]));
      }
    }
    __syncthreads();
  }

#pragma unroll
  for (int m = 0; m < 4; ++m) {
#pragma unroll
    for (int n = 0; n < 2; ++n) {
#pragma unroll
      for (int q = 0; q < 4; ++q) {
        int row = m0 + m * 16 + fg * 4 + q;
        int col = n0 + wave * 32 + n * 16 + fr;
        C[(size_t)row * DM_N + col] = acc[m][n][q];
      }
    }
  }
}

// ---------------------------------------------------------------------------
// Depthwise causal conv (DC=4) + bias, times silu(z). float4 over channels.
// ---------------------------------------------------------------------------
__global__ __launch_bounds__(256) void conv_silu_kernel(
    const float* __restrict__ xz, const float* __restrict__ cw,
    const float* __restrict__ cb, float* __restrict__ u2) {
  int idx = blockIdx.x * 256 + threadIdx.x;  // < NTOK*DI/4 = 2097152
  int i4 = idx & (DI_N / 4 - 1);
  int n = idx >> 9;
  int i = i4 << 2;
  int l = n & (L_N - 1);
  const float* base = xz + (size_t)n * (2 * DI_N) + i;
  float4 zero = {0.f, 0.f, 0.f, 0.f};
  float4 u0 = *(const float4*)base;
  float4 u1 = (l >= 1) ? *(const float4*)(base - 2 * DI_N) : zero;
  float4 um2 = (l >= 2) ? *(const float4*)(base - 4 * DI_N) : zero;
  float4 um3 = (l >= 3) ? *(const float4*)(base - 6 * DI_N) : zero;
  float4 z = *(const float4*)(base + DI_N);
  float4 bia = *(const float4*)&cb[i];
  float4 w0 = *(const float4*)&cw[i * 4];
  float4 w1 = *(const float4*)&cw[i * 4 + 4];
  float4 w2 = *(const float4*)&cw[i * 4 + 8];
  float4 w3 = *(const float4*)&cw[i * 4 + 12];
  float4 r;
  r.x = fmaf(w0.w, u0.x, fmaf(w0.z, u1.x, fmaf(w0.y, um2.x, fmaf(w0.x, um3.x, bia.x))));
  r.y = fmaf(w1.w, u0.y, fmaf(w1.z, u1.y, fmaf(w1.y, um2.y, fmaf(w1.x, um3.y, bia.y))));
  r.z = fmaf(w2.w, u0.z, fmaf(w2.z, u1.z, fmaf(w2.y, um2.z, fmaf(w2.x, um3.z, bia.z))));
  r.w = fmaf(w3.w, u0.w, fmaf(w3.z, u1.w, fmaf(w3.y, um2.w, fmaf(w3.x, um3.w, bia.w))));
  r.x *= z.x / (1.f + __expf(-z.x));
  r.y *= z.y / (1.f + __expf(-z.y));
  r.z *= z.z / (1.f + __expf(-z.z));
  r.w *= z.w / (1.f + __expf(-z.w));
  *(float4*)&u2[(size_t)n * DI_N + i] = r;
}

// ---------------------------------------------------------------------------
// xproj stage 1: partials into padded 36-wide rows (d0@0, B@4..19, C@20..35).
// ---------------------------------------------------------------------------
__global__ __launch_bounds__(256) void xproj_part_kernel(
    const float* __restrict__ u2, const float* __restrict__ xw,
    float* __restrict__ part) {
  __shared__ float uS[16][257];
  __shared__ float wS[33][257];
  const int tid = threadIdx.x;
  const int kc = blockIdx.x & (XKC - 1);
  const int rb = blockIdx.x >> 3;
  const int row0 = rb * 16;
  const int k0 = kc * XKCL;

#pragma unroll
  for (int it = 0; it < 4; ++it) {
    int slot = tid + it * 256;
    int r = slot >> 6;
    int kq = (slot & 63) << 2;
    float4 v = *(const float4*)&u2[(size_t)(row0 + r) * DI_N + k0 + kq];
    uS[r][kq] = v.x; uS[r][kq + 1] = v.y;
    uS[r][kq + 2] = v.z; uS[r][kq + 3] = v.w;
  }
#pragma unroll
  for (int it = 0; it < 9; ++it) {
    int slot = tid + it * 256;
    if (slot < 33 * 64) {
      int c = slot >> 6;
      int kq = (slot & 63) << 2;
      float4 v = *(const float4*)&xw[(size_t)c * DI_N + k0 + kq];
      wS[c][kq] = v.x; wS[c][kq + 1] = v.y;
      wS[c][kq + 2] = v.z; wS[c][kq + 3] = v.w;
    }
  }
  __syncthreads();

  const int r = tid & 15;
  const int cg = tid >> 4;
  const int c0 = cg * 3;
  const int rc0 = c0 > 32 ? 32 : c0;
  const int rc1 = c0 + 1 > 32 ? 32 : c0 + 1;
  const int rc2 = c0 + 2 > 32 ? 32 : c0 + 2;
  float a0 = 0.f, a1 = 0.f, a2 = 0.f;
#pragma unroll 4
  for (int k = 0; k < XKCL; ++k) {
    float uv = uS[r][k];
    a0 = fmaf(uv, wS[rc0][k], a0);
    a1 = fmaf(uv, wS[rc1][k], a1);
    a2 = fmaf(uv, wS[rc2][k], a2);
  }
  size_t base = (size_t)kc * (NTOK * NPJ) + (size_t)(row0 + r) * NPJ;
  if (c0 < NPROJ)     part[base + (c0 == 0 ? 0 : c0 + 3)] = a0;
  if (c0 + 1 < NPROJ) part[base + c0 + 4] = a1;
  if (c0 + 2 < NPROJ) part[base + c0 + 5] = a2;
  if (cg == 11) {  // zero the padding slots 1..3 (deterministic)
    part[base + 1] = 0.f; part[base + 2] = 0.f; part[base + 3] = 0.f;
  }
}

// ---------------------------------------------------------------------------
// xproj stage 2: proj36 = sum over the 8 K-chunk partials (fixed order).
// ---------------------------------------------------------------------------
__global__ __launch_bounds__(256) void xproj_reduce_kernel(
    const float* __restrict__ part, float* __restrict__ proj) {
  int idx = blockIdx.x * 256 + threadIdx.x;  // < NTOK*NPJ = 147456
  float s = 0.f;
#pragma unroll
  for (int kc = 0; kc < XKC; ++kc)
    s += part[(size_t)kc * (NTOK * NPJ) + idx];
  proj[idx] = s;
}

// ---------------------------------------------------------------------------
// Scan pass 1: block = (b, chunk, 256 i-channels). proj chunk staged in LDS.
// ---------------------------------------------------------------------------
__global__ __launch_bounds__(256) void scan_pass1_kernel(
    const float* __restrict__ u2, const float* __restrict__ pj,
    const float* __restrict__ dtw, const float* __restrict__ dtb,
    const float* __restrict__ A_log,
    float* __restrict__ carryH, float* __restrict__ sdteO) {
  __shared__ float pS[CL][20];
  const int tid = threadIdx.x;
  const int bid = blockIdx.x;
  const int ib = bid & 7;
  const int c = (bid >> 3) & (NC - 1);
  const int b = bid >> 9;
  const int i = ib * 256 + tid;
  const int l0 = c * CL;
  const float LOG2E = 1.4426950408889634f;

  if (tid < CL * 5) {
    int row = tid / 5, j = tid % 5;
    float4 v = *(const float4*)&pj[((size_t)b * L_N + l0 + row) * NPJ + j * 4];
    *(float4*)&pS[row][j * 4] = v;
  }

  float A2[16];
#pragma unroll
  for (int q = 0; q < 4; ++q) {
    float4 v = *(const float4*)&A_log[i * DS_N + q * 4];
    A2[q * 4 + 0] = -__expf(v.x) * LOG2E;
    A2[q * 4 + 1] = -__expf(v.y) * LOG2E;
    A2[q * 4 + 2] = -__expf(v.z) * LOG2E;
    A2[q * 4 + 3] = -__expf(v.w) * LOG2E;
  }
  const float wl = dtw[i] * LOG2E;
  const float bl = dtb[i] * LOG2E;
  const float* un = u2 + ((size_t)b * L_N + l0) * DI_N + i;
  __syncthreads();

  float h[16] = {};
  float sdte = 0.f;
  float ucur = un[0];
#pragma unroll 2
  for (int l = 0; l < CL; ++l) {
    float unext = (l + 1 < CL) ? un[(size_t)(l + 1) * DI_N] : 0.f;
    float d0 = pS[l][0];
    float4 B0 = *(const float4*)&pS[l][4];
    float4 B1 = *(const float4*)&pS[l][8];
    float4 B2 = *(const float4*)&pS[l][12];
    float4 B3 = *(const float4*)&pS[l][16];
    float dte = 1.f + exp2f(fmaf(d0, wl, bl));
    float du = dte * ucur;
    sdte += dte;
    float Bv[16] = {B0.x, B0.y, B0.z, B0.w, B1.x, B1.y, B1.z, B1.w,
                    B2.x, B2.y, B2.z, B2.w, B3.x, B3.y, B3.z, B3.w};
#pragma unroll
    for (int s = 0; s < 16; ++s) {
      float a = exp2f(A2[s] * dte);
      h[s] = fmaf(a, h[s], Bv[s] * du);
    }
    ucur = unext;
  }
  size_t cbase = (((size_t)c * B_N + b) * DI_N + i) * DS_N;
#pragma unroll
  for (int q = 0; q < 4; ++q) {
    float4 hv = {h[q * 4], h[q * 4 + 1], h[q * 4 + 2], h[q * 4 + 3]};
    *(float4*)&carryH[cbase + q * 4] = hv;
  }
  sdteO[((size_t)c * B_N + b) * DI_N + i] = sdte;
}

// ---------------------------------------------------------------------------
// Fixup: chain chunk carries; carryH[c] <- incoming state for chunk c.
// ---------------------------------------------------------------------------
__global__ __launch_bounds__(256) void scan_fixup_kernel(
    float* __restrict__ carryH, const float* __restrict__ sdte,
    const float* __restrict__ A_log) {
  const int q = blockIdx.x * 256 + threadIdx.x;  // < B*DI*DS = 65536
  const int s = q & 15;
  const int i = (q >> 4) & (DI_N - 1);
  const float LOG2E = 1.4426950408889634f;
  const float A2 = -__expf(A_log[i * DS_N + s]) * LOG2E;
  float h = 0.f;
#pragma unroll 8
  for (int c = 0; c < NC; ++c) {
    size_t idx = (size_t)c * (B_N * DI_N * DS_N) + q;
    float Hc = carryH[idx];
    float sd = sdte[(size_t)c * (B_N * DI_N) + (q >> 4)];
    carryH[idx] = h;
    h = fmaf(exp2f(A2 * sd), h, Hc);
  }
}

// ---------------------------------------------------------------------------
// Scan pass 2: block = (b, chunk, 256 i); proj chunk in LDS; packed y out.
// ---------------------------------------------------------------------------
__global__ __launch_bounds__(256) void scan_pass2_kernel(
    const float* __restrict__ u2, const float* __restrict__ pj,
    const float* __restrict__ dtw, const float* __restrict__ dtb,
    const float* __restrict__ A_log, const float* __restrict__ Dp,
    const float* __restrict__ carryH, char* __restrict__ ypk) {
  __shared__ float pS[CL][36];
  const int tid = threadIdx.x;
  const int bid = blockIdx.x;
  const int ib = bid & 7;
  const int c = (bid >> 3) & (NC - 1);
  const int b = bid >> 9;
  const int i = ib * 256 + tid;
  const int l0 = c * CL;
  const float LOG2E = 1.4426950408889634f;

#pragma unroll
  for (int it = 0; it < 2; ++it) {
    int slot = tid + it * 256;
    if (slot < CL * 9) {
      int row = slot / 9, j = slot % 9;
      float4 v = *(const float4*)&pj[((size_t)b * L_N + l0 + row) * NPJ + j * 4];
      *(float4*)&pS[row][j * 4] = v;
    }
  }

  float A2[16];
#pragma unroll
  for (int q = 0; q < 4; ++q) {
    float4 v = *(const float4*)&A_log[i * DS_N + q * 4];
    A2[q * 4 + 0] = -__expf(v.x) * LOG2E;
    A2[q * 4 + 1] = -__expf(v.y) * LOG2E;
    A2[q * 4 + 2] = -__expf(v.z) * LOG2E;
    A2[q * 4 + 3] = -__expf(v.w) * LOG2E;
  }
  const float wl = dtw[i] * LOG2E;
  const float bl = dtb[i] * LOG2E;
  const float Dd = Dp[i];

  float h[16];
  size_t cbase = (((size_t)c * B_N + b) * DI_N + i) * DS_N;
#pragma unroll
  for (int q = 0; q < 4; ++q) {
    float4 hv = *(const float4*)&carryH[cbase + q * 4];
    h[q * 4] = hv.x; h[q * 4 + 1] = hv.y;
    h[q * 4 + 2] = hv.z; h[q * 4 + 3] = hv.w;
  }

  const float* un = u2 + ((size_t)b * L_N + l0) * DI_N + i;
  char* yb = ypk + ((size_t)b * L_N + l0) * (DI_N * 4) + (i >> 3) * 32 + (i & 7) * 2;
  __syncthreads();

  float ucur = un[0];
#pragma unroll 2
  for (int l = 0; l < CL; ++l) {
    float unext = (l + 1 < CL) ? un[(size_t)(l + 1) * DI_N] : 0.f;
    float d0 = pS[l][0];
    float4 B0 = *(const float4*)&pS[l][4];
    float4 B1 = *(const float4*)&pS[l][8];
    float4 B2 = *(const float4*)&pS[l][12];
    float4 B3 = *(const float4*)&pS[l][16];
    float4 C0 = *(const float4*)&pS[l][20];
    float4 C1 = *(const float4*)&pS[l][24];
    float4 C2 = *(const float4*)&pS[l][28];
    float4 C3 = *(const float4*)&pS[l][32];
    float dte = 1.f + exp2f(fmaf(d0, wl, bl));
    float du = dte * ucur;
    float Bv[16] = {B0.x, B0.y, B0.z, B0.w, B1.x, B1.y, B1.z, B1.w,
                    B2.x, B2.y, B2.z, B2.w, B3.x, B3.y, B3.z, B3.w};
    float Cv[16] = {C0.x, C0.y, C0.z, C0.w, C1.x, C1.y, C1.z, C1.w,
                    C2.x, C2.y, C2.z, C2.w, C3.x, C3.y, C3.z, C3.w};
    float y = Dd * ucur;
#pragma unroll
    for (int s = 0; s < 16; ++s) {
      float a = exp2f(A2[s] * dte);
      h[s] = fmaf(a, h[s], Bv[s] * du);
      y = fmaf(h[s], Cv[s], y);
    }
    unsigned short hh = f2bf_rn(y);
    char* q = yb + (size_t)l * (DI_N * 4);
    *(unsigned short*)q = hh;
    *(unsigned short*)(q + 16) = f2bf_rn(y - bf2f(hh));
    ucur = unext;
  }
}

// ---------------------------------------------------------------------------
extern "C" void kernel_launch(void* const* d_in, const int* in_sizes, int n_in,
                              void* d_out, int out_size, void* d_ws, size_t ws_size,
                              hipStream_t stream) {
  const float* x          = (const float*)d_in[0];
  const float* in_proj_w  = (const float*)d_in[1];
  const float* conv_w     = (const float*)d_in[2];
  const float* conv_b     = (const float*)d_in[3];
  const float* x_proj_w   = (const float*)d_in[4];
  const float* dt_proj_w  = (const float*)d_in[5];
  const float* dt_proj_b  = (const float*)d_in[6];
  const float* A_log      = (const float*)d_in[7];
  const float* Dp         = (const float*)d_in[8];
  const float* out_proj_w = (const float*)d_in[9];
  float* out = (float*)d_out;

  char* ws = (char*)d_ws;
  float* xz = (float*)ws;                                  // [0, 67.11MB)
  float* u2 = (float*)(ws + (size_t)NTOK * 2 * DI_N * 4);  // [67.11, 100.66)

  // packed x / in_proj_w live in the u2 region (dead until conv_silu)
  char* x_pk  = (char*)u2;                                 // 16.78MB
  char* w1_pk = x_pk + (size_t)NTOK * DM_N * 4;            // 16.78MB

  // xz region reuse after conv_silu (all within [0, 67.11MB))
  char*  y_pk   = ws;                                      // 33.55MB
  float* carryH = (float*)(ws + 33554432);                 // 16.78MB
  float* sdte   = (float*)(ws + 50331648);                 // 1.05MB
  char*  w2_pk  = ws + 51380224;                           // 8.39MB
  float* xpart  = (float*)(ws + 59768832);                 // 4.72MB
  float* proj36 = (float*)(ws + 64487424);                 // 0.59MB

  // 1) split+pack x and in_proj_w
  {
    int n8 = NTOK * DM_N / 8;  // 524288
    split_pack_kernel<<<n8 / 256, 256, 0, stream>>>(x, (uint32_t*)x_pk, n8);
    split_pack_kernel<<<n8 / 256, 256, 0, stream>>>(in_proj_w, (uint32_t*)w1_pk, n8);
  }
  // 2) xz = x @ in_proj_w.T : M=4096 N=4096 K=1024, grid 1024
  gemm_pk_nt<<<1024, 256, 0, stream>>>(x_pk, w1_pk, xz, 2 * DI_N, DM_N * 4, 32);
  // 3) conv + silu (float4 channels)
  conv_silu_kernel<<<(NTOK * DI_N / 4) / 256, 256, 0, stream>>>(xz, conv_w,
                                                                conv_b, u2);
  // 4) split+pack out_proj_w
  {
    int n8 = DM_N * DI_N / 8;  // 262144
    split_pack_kernel<<<n8 / 256, 256, 0, stream>>>(out_proj_w, (uint32_t*)w2_pk, n8);
  }
  // 5) proj36 = u2 @ x_proj_w.T  (2-stage K-split, padded rows)
  {
    xproj_part_kernel<<<(NTOK / 16) * XKC, 256, 0, stream>>>(u2, x_proj_w, xpart);
    xproj_reduce_kernel<<<(NTOK * NPJ) / 256, 256, 0, stream>>>(xpart, proj36);
  }
  // 6) chunked selective scan -> packed y
  {
    int nblk = B_N * NC * (DI_N / 256);  // 1024
    scan_pass1_kernel<<<nblk, 256, 0, stream>>>(u2, proj36, dt_proj_w, dt_proj_b,
                                                A_log, carryH, sdte);
    scan_fixup_kernel<<<(B_N * DI_N * DS_N) / 256, 256, 0, stream>>>(carryH, sdte,
                                                                     A_log);
    scan_pass2_kernel<<<nblk, 256, 0, stream>>>(u2, proj36, dt_proj_w, dt_proj_b,
                                                A_log, Dp, carryH, y_pk);
  }
  // 7) out = y @ out_proj_w.T : M=4096 N=1024 K=2048, tile 64x128, grid 512
  gemm2_pk_nt<<<512, 256, 0, stream>>>(y_pk, w2_pk, out);
}